// Round 1
// baseline (559.379 us; speedup 1.0000x reference)
//
#include <hip/hip_runtime.h>
#include <stdint.h>

// Shapes (fixed by the problem)
#define Bc   2
#define Tc   2048
#define Cc   2048
#define Hc   16
#define Dc   128
#define BT   4096      // B*T
#define N3   6144      // 3*C
#define QSCALE 0.08838834764831845f  // 1/sqrt(128)

typedef _Float16 f16x8 __attribute__((ext_vector_type(8)));
typedef _Float16 f16x4 __attribute__((ext_vector_type(4)));
typedef float    f32x4 __attribute__((ext_vector_type(4)));

__device__ __forceinline__ void gload_lds16(const void* g, void* l) {
  __builtin_amdgcn_global_load_lds(
      (__attribute__((address_space(1))) void*)(uintptr_t)g,
      (__attribute__((address_space(3))) void*)(unsigned int)(uintptr_t)l,
      16, 0, 0);
}

// ---------------- fp32 -> fp16 cast (vectorized) ----------------
__global__ __launch_bounds__(256) void cvt_f16_kernel(const float* __restrict__ in,
                                                      _Float16* __restrict__ out, int n4) {
  int i = blockIdx.x * 256 + threadIdx.x;
  if (i < n4) {
    float4 v = ((const float4*)in)[i];
    f16x4 o; o[0]=(_Float16)v.x; o[1]=(_Float16)v.y; o[2]=(_Float16)v.z; o[3]=(_Float16)v.w;
    ((f16x4*)out)[i] = o;
  }
}

// ---------------- W [K][N] fp32 -> Wt [N][K] fp16 (LDS-tiled transpose) ----------------
__global__ __launch_bounds__(256) void transpose_cvt_kernel(const float* __restrict__ W,
                                                            _Float16* __restrict__ Wt,
                                                            int K, int N) {
  const int n0 = blockIdx.x * 64, k0 = blockIdx.y * 64;
  __shared__ float tile[64][65];
  const int tid = threadIdx.x;
  #pragma unroll
  for (int i = 0; i < 4; ++i) {               // load 64x64 f32, coalesced rows
    int u = i * 256 + tid, r = u >> 4, s = u & 15;
    float4 v = *(const float4*)&W[(size_t)(k0 + r) * N + n0 + s * 4];
    tile[r][s*4+0] = v.x; tile[r][s*4+1] = v.y; tile[r][s*4+2] = v.z; tile[r][s*4+3] = v.w;
  }
  __syncthreads();
  #pragma unroll
  for (int i = 0; i < 2; ++i) {               // write 64 n-rows of 64 fp16, coalesced
    int u = i * 256 + tid, c = u >> 3, rg = u & 7;
    f16x8 o;
    #pragma unroll
    for (int j = 0; j < 8; ++j) o[j] = (_Float16)tile[rg * 8 + j][c];
    *(f16x8*)&Wt[(size_t)(n0 + c) * K + k0 + rg * 8] = o;
  }
}

// ---------------- GEMM: C[M][N] = A[M][K] * Bt[N][K]^T  (fp16 in, fp32 acc) ----------------
template<bool OUT16>
__global__ __launch_bounds__(256) void gemm_bt_kernel(const _Float16* __restrict__ A,
                                                      const _Float16* __restrict__ Bt,
                                                      void* __restrict__ C,
                                                      int M, int N, int K) {
  const int tid = threadIdx.x;
  const int w = tid >> 6, lane = tid & 63, g = lane >> 4, c16 = lane & 15;
  const int m0 = blockIdx.y * 128, n0 = blockIdx.x * 128;
  const int wm = (w >> 1) * 64, wn = (w & 1) * 64;

  __shared__ __align__(16) _Float16 Alds[128 * 32];
  __shared__ __align__(16) _Float16 Blds[128 * 32];

  const int r4 = lane >> 2, k8 = (lane & 3) * 8;     // staging: row-in-chunk, k-offset
  const char* aSrc = (const char*)(A + (size_t)(m0 + r4) * K + k8);
  const char* bSrc = (const char*)(Bt + (size_t)(n0 + r4) * K + k8);

  f32x4 acc[4][4] = {};

  for (int k0 = 0; k0 < K; k0 += 32) {
    __syncthreads();
    #pragma unroll
    for (int j = 0; j < 2; ++j) {
      int ch = j * 4 + w;                            // 8 chunks of 1KB each for A and B
      gload_lds16(aSrc + ((size_t)ch * 16 * K + k0) * 2, (char*)Alds + ch * 1024);
      gload_lds16(bSrc + ((size_t)ch * 16 * K + k0) * 2, (char*)Blds + ch * 1024);
    }
    __syncthreads();
    f16x8 af[4], bf[4];
    #pragma unroll
    for (int i = 0; i < 4; ++i) {
      af[i] = *(const f16x8*)&Alds[(wm + i * 16 + c16) * 32 + g * 8];
      bf[i] = *(const f16x8*)&Blds[(wn + i * 16 + c16) * 32 + g * 8];
    }
    #pragma unroll
    for (int mi = 0; mi < 4; ++mi)
      #pragma unroll
      for (int ni = 0; ni < 4; ++ni)
        acc[mi][ni] = __builtin_amdgcn_mfma_f32_16x16x32_f16(af[mi], bf[ni], acc[mi][ni], 0, 0, 0);
  }

  #pragma unroll
  for (int mi = 0; mi < 4; ++mi)
    #pragma unroll
    for (int ni = 0; ni < 4; ++ni) {
      int row = m0 + wm + mi * 16 + g * 4;
      int col = n0 + wn + ni * 16 + c16;
      #pragma unroll
      for (int r = 0; r < 4; ++r) {
        if constexpr (OUT16) ((_Float16*)C)[(size_t)(row + r) * N + col] = (_Float16)acc[mi][ni][r];
        else                 ((float*)C)[(size_t)(row + r) * N + col]    = acc[mi][ni][r];
      }
    }
}

// ---------------- RoPE on q,k; fold softmax scale into Q; K stored bank-swizzled ----------------
__global__ __launch_bounds__(256) void rope_qk_kernel(const _Float16* __restrict__ qkv,
                                                      const float* __restrict__ cosT,
                                                      const float* __restrict__ sinT,
                                                      _Float16* __restrict__ Qr,
                                                      _Float16* __restrict__ Kr) {
  const int bt = blockIdx.x;                 // b*T + t
  const int b = bt >> 11, t = bt & 2047;
  const int tid = threadIdx.x;
  const _Float16* row = qkv + (size_t)bt * N3;
  const int sw = (t & 7) * 8;
  #pragma unroll
  for (int i = 0; i < 4; ++i) {
    int p = i * 256 + tid;                   // pair index: h = p/64, d = p%64 (d < 64)
    int h = p >> 6, d = p & 63;
    float cs = cosT[t * Dc + d], sn = sinT[t * Dc + d];
    float ql = (float)row[h * Dc + d],        qh = (float)row[h * Dc + d + 64];
    float kl = (float)row[Cc + h * Dc + d],   kh = (float)row[Cc + h * Dc + d + 64];
    float q0 = ql * cs - qh * sn, q1 = qh * cs + ql * sn;
    float k0 = kl * cs - kh * sn, k1 = kh * cs + kl * sn;
    size_t obase = ((size_t)(b * Hc + h) * Tc + t) * Dc;
    Qr[obase + d]        = (_Float16)(q0 * QSCALE);
    Qr[obase + d + 64]   = (_Float16)(q1 * QSCALE);
    Kr[obase + (d ^ sw)]        = (_Float16)k0;    // pre-baked XOR swizzle
    Kr[obase + ((d + 64) ^ sw)] = (_Float16)k1;
  }
}

// ---------------- V transpose: qkv v-part -> Vt[B][H][D][T] fp16, pre-swizzled ----------------
__global__ __launch_bounds__(256) void vtrans_kernel(const _Float16* __restrict__ qkv,
                                                     _Float16* __restrict__ Vt) {
  const int t0 = blockIdx.x * 64, d0 = blockIdx.y * 64, bh = blockIdx.z;
  const int b = bh >> 4, h = bh & 15;
  __shared__ __align__(16) _Float16 tile[64][72];
  const int tid = threadIdx.x;
  #pragma unroll
  for (int i = 0; i < 2; ++i) {
    int u = i * 256 + tid, tr = u >> 3, sg = u & 7;
    f16x8 v = *(const f16x8*)&qkv[((size_t)b * Tc + t0 + tr) * N3 + 2 * Cc + h * Dc + d0 + sg * 8];
    *(f16x8*)&tile[tr][sg * 8] = v;
  }
  __syncthreads();
  #pragma unroll
  for (int i = 0; i < 2; ++i) {
    int u = i * 256 + tid, dl = u >> 3, tg = u & 7;
    int d = d0 + dl;
    f16x8 o;
    #pragma unroll
    for (int j = 0; j < 8; ++j) o[j] = tile[tg * 8 + j][dl];
    size_t off = ((size_t)bh * Dc + d) * Tc + t0 + ((tg ^ (d & 7)) * 8);  // swizzled t
    *(f16x8*)&Vt[off] = o;
  }
}

// ---------------- Flash attention (causal). 128 q-rows/block, 4 waves x 32 rows ----------------
__global__ __launch_bounds__(256) void attn_kernel(const _Float16* __restrict__ Qr,
                                                   const _Float16* __restrict__ Kr,
                                                   const _Float16* __restrict__ Vt,
                                                   _Float16* __restrict__ Oh) {
  const int qt = blockIdx.x, bh = blockIdx.y;
  const int tid = threadIdx.x;
  const int w = tid >> 6, lane = tid & 63, g = lane >> 4, c16 = lane & 15, l7 = lane & 7;
  const int wq0 = qt * 128 + w * 32;

  __shared__ __align__(16) _Float16 Klds[64 * 128];   // [kv][d] (data pre-swizzled)
  __shared__ __align__(16) _Float16 Vlds[128 * 64];   // [d][kv] (data pre-swizzled)
  __shared__ __align__(16) _Float16 Plds[4][32][72];  // per-wave P, padded

  // Q fragments in registers (scale already folded in)
  f16x8 qf[2][4];
  const _Float16* Qb = Qr + (size_t)bh * Tc * Dc;
  #pragma unroll
  for (int mi = 0; mi < 2; ++mi)
    #pragma unroll
    for (int kb = 0; kb < 4; ++kb)
      qf[mi][kb] = *(const f16x8*)&Qb[(size_t)(wq0 + mi * 16 + c16) * Dc + kb * 32 + g * 8];

  f32x4 acc_o[2][8] = {};
  float m_run[2][4], l_run[2][4];
  #pragma unroll
  for (int mi = 0; mi < 2; ++mi)
    #pragma unroll
    for (int r = 0; r < 4; ++r) { m_run[mi][r] = -1e30f; l_run[mi][r] = 0.0f; }

  const _Float16* Kt0 = Kr + (size_t)bh * Tc * Dc;
  const int nt = 2 * qt + 2;

  for (int it = 0; it < nt; ++it) {
    const int kv0 = it * 64;
    __syncthreads();                                  // prev compute done
    {   // stage K tile: 16KB contiguous in global
      const char* src = (const char*)(Kt0 + (size_t)kv0 * Dc);
      #pragma unroll
      for (int j = 0; j < 4; ++j) {
        int ch = j * 4 + w;
        gload_lds16(src + ch * 1024 + lane * 16, (char*)Klds + ch * 1024);
      }
      // stage V tile: 128 rows of 128B (stride T*2)
      #pragma unroll
      for (int j = 0; j < 4; ++j) {
        int ch = j * 4 + w;
        int d = ch * 8 + (lane >> 3);
        const char* gs = (const char*)(Vt + ((size_t)bh * Dc + d) * Tc + kv0) + (lane & 7) * 16;
        gload_lds16(gs, (char*)Vlds + ch * 1024);
      }
    }
    __syncthreads();                                  // data ready
    if (kv0 > wq0 + 31) continue;                     // fully-masked for this wave

    // ---- S = Q K^T ----
    f32x4 sc[2][4] = {};
    #pragma unroll
    for (int kb = 0; kb < 4; ++kb) {
      f16x8 bfr[4];
      #pragma unroll
      for (int ni = 0; ni < 4; ++ni) {
        int row = ni * 16 + c16;
        int e = ((kb * 4 + g) ^ l7) * 8;              // swizzled read offset
        bfr[ni] = *(const f16x8*)&Klds[row * 128 + e];
      }
      #pragma unroll
      for (int mi = 0; mi < 2; ++mi)
        #pragma unroll
        for (int ni = 0; ni < 4; ++ni)
          sc[mi][ni] = __builtin_amdgcn_mfma_f32_16x16x32_f16(qf[mi][kb], bfr[ni], sc[mi][ni], 0, 0, 0);
    }
    // ---- causal mask ----
    if (kv0 + 63 > wq0) {
      #pragma unroll
      for (int mi = 0; mi < 2; ++mi)
        #pragma unroll
        for (int ni = 0; ni < 4; ++ni)
          #pragma unroll
          for (int r = 0; r < 4; ++r) {
            int q = wq0 + mi * 16 + g * 4 + r;
            int kv = kv0 + ni * 16 + c16;
            if (kv > q) sc[mi][ni][r] = -1e30f;
          }
    }
    // ---- online softmax ----
    #pragma unroll
    for (int mi = 0; mi < 2; ++mi)
      #pragma unroll
      for (int r = 0; r < 4; ++r) {
        float mt = sc[mi][0][r];
        mt = fmaxf(mt, sc[mi][1][r]); mt = fmaxf(mt, sc[mi][2][r]); mt = fmaxf(mt, sc[mi][3][r]);
        #pragma unroll
        for (int off = 1; off < 16; off <<= 1) mt = fmaxf(mt, __shfl_xor(mt, off));
        float mnew = fmaxf(m_run[mi][r], mt);
        float alpha = __expf(m_run[mi][r] - mnew);
        float ps0 = __expf(sc[mi][0][r] - mnew), ps1 = __expf(sc[mi][1][r] - mnew);
        float ps2 = __expf(sc[mi][2][r] - mnew), ps3 = __expf(sc[mi][3][r] - mnew);
        float ls = ps0 + ps1 + ps2 + ps3;
        #pragma unroll
        for (int off = 1; off < 16; off <<= 1) ls += __shfl_xor(ls, off);
        l_run[mi][r] = l_run[mi][r] * alpha + ls;
        m_run[mi][r] = mnew;
        #pragma unroll
        for (int di = 0; di < 8; ++di) acc_o[mi][di][r] *= alpha;
        int prow = mi * 16 + g * 4 + r;
        Plds[w][prow][0  + c16] = (_Float16)ps0;
        Plds[w][prow][16 + c16] = (_Float16)ps1;
        Plds[w][prow][32 + c16] = (_Float16)ps2;
        Plds[w][prow][48 + c16] = (_Float16)ps3;
      }
    // ---- O += P V ----
    #pragma unroll
    for (int kvb = 0; kvb < 2; ++kvb) {
      f16x8 pf[2];
      #pragma unroll
      for (int mi = 0; mi < 2; ++mi)
        pf[mi] = *(const f16x8*)&Plds[w][mi * 16 + c16][kvb * 32 + g * 8];
      #pragma unroll
      for (int di = 0; di < 8; ++di) {
        int row = di * 16 + c16;
        int e = ((kvb * 4 + g) ^ l7) * 8;             // swizzled read offset
        f16x8 vf = *(const f16x8*)&Vlds[row * 64 + e];
        #pragma unroll
        for (int mi = 0; mi < 2; ++mi)
          acc_o[mi][di] = __builtin_amdgcn_mfma_f32_16x16x32_f16(pf[mi], vf, acc_o[mi][di], 0, 0, 0);
      }
    }
  }

  // ---- epilogue: O /= l, write [B][T][C] fp16 ----
  const int b = bh >> 4, h = bh & 15;
  #pragma unroll
  for (int mi = 0; mi < 2; ++mi)
    #pragma unroll
    for (int r = 0; r < 4; ++r) {
      float inv = 1.0f / l_run[mi][r];
      int trow = qt * 128 + w * 32 + mi * 16 + g * 4 + r;
      _Float16* orow = Oh + ((size_t)b * Tc + trow) * Cc + h * Dc;
      #pragma unroll
      for (int di = 0; di < 8; ++di)
        orow[di * 16 + c16] = (_Float16)(acc_o[mi][di][r] * inv);
    }
}

// ---------------- host launch ----------------
extern "C" void kernel_launch(void* const* d_in, const int* in_sizes, int n_in,
                              void* d_out, int out_size, void* d_ws, size_t ws_size,
                              hipStream_t stream) {
  const float* x      = (const float*)d_in[0];
  const float* cosT   = (const float*)d_in[1];
  const float* sinT   = (const float*)d_in[2];
  const float* W_attn = (const float*)d_in[3];
  const float* W_proj = (const float*)d_in[4];
  float* out = (float*)d_out;

  // workspace layout (bytes)
  const size_t OFF_XH   = 0;                       // 4096*2048*2   = 16,777,216
  const size_t OFF_WAH  = 16777216;                // 6144*2048*2   = 25,165,824
  const size_t OFF_WPH  = 41943040;                // 2048*2048*2   =  8,388,608
  const size_t OFF_QKV  = 50331648;                // 4096*6144*2   = 50,331,648
  const size_t OFF_QR   = 100663296;               // 16,777,216
  const size_t OFF_KR   = 117440512;               // 16,777,216
  const size_t OFF_VT   = 134217728;               // 16,777,216
  const size_t WS_NEEDED = 150994944;
  if (ws_size < WS_NEEDED) return;

  char* ws = (char*)d_ws;
  _Float16* xh   = (_Float16*)(ws + OFF_XH);
  _Float16* Wah  = (_Float16*)(ws + OFF_WAH);
  _Float16* Wph  = (_Float16*)(ws + OFF_WPH);
  _Float16* qkvh = (_Float16*)(ws + OFF_QKV);
  _Float16* Qr   = (_Float16*)(ws + OFF_QR);
  _Float16* Kr   = (_Float16*)(ws + OFF_KR);
  _Float16* Vt   = (_Float16*)(ws + OFF_VT);
  _Float16* Oh   = qkvh;   // reuse qkv buffer for attention output

  cvt_f16_kernel<<<dim3(8192), dim3(256), 0, stream>>>(x, xh, (Bc * Tc * Cc) / 4);
  transpose_cvt_kernel<<<dim3(N3 / 64, Cc / 64), dim3(256), 0, stream>>>(W_attn, Wah, Cc, N3);
  transpose_cvt_kernel<<<dim3(Cc / 64, Cc / 64), dim3(256), 0, stream>>>(W_proj, Wph, Cc, Cc);
  gemm_bt_kernel<true><<<dim3(N3 / 128, BT / 128), dim3(256), 0, stream>>>(xh, Wah, qkvh, BT, N3, Cc);
  rope_qk_kernel<<<dim3(BT), dim3(256), 0, stream>>>(qkvh, cosT, sinT, Qr, Kr);
  vtrans_kernel<<<dim3(Tc / 64, Dc / 64, Bc * Hc), dim3(256), 0, stream>>>(qkvh, Vt);
  attn_kernel<<<dim3(Tc / 128, Bc * Hc), dim3(256), 0, stream>>>(Qr, Kr, Vt, Oh);
  gemm_bt_kernel<false><<<dim3(Cc / 128, BT / 128), dim3(256), 0, stream>>>(Oh, Wph, out, BT, Cc, Cc);
}

// Round 5
// 447.798 us; speedup vs baseline: 1.2492x; 1.2492x over previous
//
#include <hip/hip_runtime.h>
#include <stdint.h>

// Shapes (fixed by the problem)
#define Bc   2
#define Tc   2048
#define Cc   2048
#define Hc   16
#define Dc   128
#define BT   4096      // B*T
#define N3   6144      // 3*C
#define QSCALE 0.08838834764831845f  // 1/sqrt(128)

typedef _Float16 f16x8 __attribute__((ext_vector_type(8)));
typedef _Float16 f16x4 __attribute__((ext_vector_type(4)));
typedef float    f32x4 __attribute__((ext_vector_type(4)));

__device__ __forceinline__ void gload_lds16(const void* g, void* l) {
  __builtin_amdgcn_global_load_lds(
      (__attribute__((address_space(1))) void*)(uintptr_t)g,
      (__attribute__((address_space(3))) void*)(unsigned int)(uintptr_t)l,
      16, 0, 0);
}

// ---------------- fp32 -> fp16 cast (vectorized) ----------------
__global__ __launch_bounds__(256) void cvt_f16_kernel(const float* __restrict__ in,
                                                      _Float16* __restrict__ out, int n4) {
  int i = blockIdx.x * 256 + threadIdx.x;
  if (i < n4) {
    float4 v = ((const float4*)in)[i];
    f16x4 o; o[0]=(_Float16)v.x; o[1]=(_Float16)v.y; o[2]=(_Float16)v.z; o[3]=(_Float16)v.w;
    ((f16x4*)out)[i] = o;
  }
}

// ---------------- W [K][N] fp32 -> Wt [N][K] fp16 (LDS-tiled transpose) ----------------
__global__ __launch_bounds__(256) void transpose_cvt_kernel(const float* __restrict__ W,
                                                            _Float16* __restrict__ Wt,
                                                            int K, int N) {
  const int n0 = blockIdx.x * 64, k0 = blockIdx.y * 64;
  __shared__ float tile[64][65];
  const int tid = threadIdx.x;
  #pragma unroll
  for (int i = 0; i < 4; ++i) {               // load 64x64 f32, coalesced rows
    int u = i * 256 + tid, r = u >> 4, s = u & 15;
    float4 v = *(const float4*)&W[(size_t)(k0 + r) * N + n0 + s * 4];
    tile[r][s*4+0] = v.x; tile[r][s*4+1] = v.y; tile[r][s*4+2] = v.z; tile[r][s*4+3] = v.w;
  }
  __syncthreads();
  #pragma unroll
  for (int i = 0; i < 2; ++i) {               // write 64 n-rows of 64 fp16, coalesced
    int u = i * 256 + tid, c = u >> 3, rg = u & 7;
    f16x8 o;
    #pragma unroll
    for (int j = 0; j < 8; ++j) o[j] = (_Float16)tile[rg * 8 + j][c];
    *(f16x8*)&Wt[(size_t)(n0 + c) * K + k0 + rg * 8] = o;
  }
}

// ---------------- GEMM: C[M][N] = A[M][K] * Bt[N][K]^T  (fp16 in, fp32 acc) ----------------
template<bool OUT16>
__global__ __launch_bounds__(256) void gemm_bt_kernel(const _Float16* __restrict__ A,
                                                      const _Float16* __restrict__ Bt,
                                                      void* __restrict__ C,
                                                      int M, int N, int K) {
  const int tid = threadIdx.x;
  const int w = tid >> 6, lane = tid & 63, g = lane >> 4, c16 = lane & 15;
  const int m0 = blockIdx.y * 128, n0 = blockIdx.x * 128;
  const int wm = (w >> 1) * 64, wn = (w & 1) * 64;

  __shared__ __align__(16) _Float16 Alds[128 * 32];
  __shared__ __align__(16) _Float16 Blds[128 * 32];

  const int r4 = lane >> 2, k8 = (lane & 3) * 8;     // staging: row-in-chunk, k-offset
  const char* aSrc = (const char*)(A + (size_t)(m0 + r4) * K + k8);
  const char* bSrc = (const char*)(Bt + (size_t)(n0 + r4) * K + k8);

  f32x4 acc[4][4] = {};

  for (int k0 = 0; k0 < K; k0 += 32) {
    __syncthreads();
    #pragma unroll
    for (int j = 0; j < 2; ++j) {
      int ch = j * 4 + w;                            // 8 chunks of 1KB each for A and B
      gload_lds16(aSrc + ((size_t)ch * 16 * K + k0) * 2, (char*)Alds + ch * 1024);
      gload_lds16(bSrc + ((size_t)ch * 16 * K + k0) * 2, (char*)Blds + ch * 1024);
    }
    __syncthreads();
    f16x8 af[4], bf[4];
    #pragma unroll
    for (int i = 0; i < 4; ++i) {
      af[i] = *(const f16x8*)&Alds[(wm + i * 16 + c16) * 32 + g * 8];
      bf[i] = *(const f16x8*)&Blds[(wn + i * 16 + c16) * 32 + g * 8];
    }
    #pragma unroll
    for (int mi = 0; mi < 4; ++mi)
      #pragma unroll
      for (int ni = 0; ni < 4; ++ni)
        acc[mi][ni] = __builtin_amdgcn_mfma_f32_16x16x32_f16(af[mi], bf[ni], acc[mi][ni], 0, 0, 0);
  }

  #pragma unroll
  for (int mi = 0; mi < 4; ++mi)
    #pragma unroll
    for (int ni = 0; ni < 4; ++ni) {
      int row = m0 + wm + mi * 16 + g * 4;
      int col = n0 + wn + ni * 16 + c16;
      #pragma unroll
      for (int r = 0; r < 4; ++r) {
        if constexpr (OUT16) ((_Float16*)C)[(size_t)(row + r) * N + col] = (_Float16)acc[mi][ni][r];
        else                 ((float*)C)[(size_t)(row + r) * N + col]    = acc[mi][ni][r];
      }
    }
}

// ---------------- RoPE on q,k; fold softmax scale into Q; K stored bank-swizzled ----------------
__global__ __launch_bounds__(256) void rope_qk_kernel(const _Float16* __restrict__ qkv,
                                                      const float* __restrict__ cosT,
                                                      const float* __restrict__ sinT,
                                                      _Float16* __restrict__ Qr,
                                                      _Float16* __restrict__ Kr) {
  const int bt = blockIdx.x;                 // b*T + t
  const int b = bt >> 11, t = bt & 2047;
  const int tid = threadIdx.x;
  const _Float16* row = qkv + (size_t)bt * N3;
  const int sw = (t & 7) * 8;
  #pragma unroll
  for (int i = 0; i < 4; ++i) {
    int p = i * 256 + tid;                   // pair index: h = p/64, d = p%64 (d < 64)
    int h = p >> 6, d = p & 63;
    float cs = cosT[t * Dc + d], sn = sinT[t * Dc + d];
    float ql = (float)row[h * Dc + d],        qh = (float)row[h * Dc + d + 64];
    float kl = (float)row[Cc + h * Dc + d],   kh = (float)row[Cc + h * Dc + d + 64];
    float q0 = ql * cs - qh * sn, q1 = qh * cs + ql * sn;
    float k0 = kl * cs - kh * sn, k1 = kh * cs + kl * sn;
    size_t obase = ((size_t)(b * Hc + h) * Tc + t) * Dc;
    Qr[obase + d]        = (_Float16)(q0 * QSCALE);
    Qr[obase + d + 64]   = (_Float16)(q1 * QSCALE);
    Kr[obase + (d ^ sw)]        = (_Float16)k0;    // pre-baked XOR swizzle
    Kr[obase + ((d + 64) ^ sw)] = (_Float16)k1;
  }
}

// ---------------- V transpose: qkv v-part -> Vt[B][H][D][T] fp16, pre-swizzled ----------------
__global__ __launch_bounds__(256) void vtrans_kernel(const _Float16* __restrict__ qkv,
                                                     _Float16* __restrict__ Vt) {
  const int t0 = blockIdx.x * 64, d0 = blockIdx.y * 64, bh = blockIdx.z;
  const int b = bh >> 4, h = bh & 15;
  __shared__ __align__(16) _Float16 tile[64][72];
  const int tid = threadIdx.x;
  #pragma unroll
  for (int i = 0; i < 2; ++i) {
    int u = i * 256 + tid, tr = u >> 3, sg = u & 7;
    f16x8 v = *(const f16x8*)&qkv[((size_t)b * Tc + t0 + tr) * N3 + 2 * Cc + h * Dc + d0 + sg * 8];
    *(f16x8*)&tile[tr][sg * 8] = v;
  }
  __syncthreads();
  #pragma unroll
  for (int i = 0; i < 2; ++i) {
    int u = i * 256 + tid, dl = u >> 3, tg = u & 7;
    int d = d0 + dl;
    f16x8 o;
    #pragma unroll
    for (int j = 0; j < 8; ++j) o[j] = tile[tg * 8 + j][dl];
    size_t off = ((size_t)bh * Dc + d) * Tc + t0 + ((tg ^ (d & 7)) * 8);  // swizzled t
    *(f16x8*)&Vt[off] = o;
  }
}

// ---------------- Flash attention (causal), balanced pairs + double-buffered staging ----
// Block handles two 64-row Q-tiles: qtA = pair, qtB = 31-pair -> 33 tile-computes/block.
// KV tiles j=0..qtB staged once, shared by both Q-tiles. One barrier per KV iter.
__global__ __launch_bounds__(256, 2) void attn_kernel(const _Float16* __restrict__ Qr,
                                                      const _Float16* __restrict__ Kr,
                                                      const _Float16* __restrict__ Vt,
                                                      _Float16* __restrict__ Oh) {
  const int bh = blockIdx.x;                 // fast dim -> XCD = bh % 8 (L2 locality)
  const int pr = blockIdx.y;                 // pair index 0..15
  const int qtA = pr, qtB = 31 - pr;
  const int tid = threadIdx.x;
  const int w = tid >> 6, lane = tid & 63, g = lane >> 4, c16 = lane & 15, l7 = lane & 7;
  const int rA = qtA * 64 + w * 16;          // wave's 16 rows in tile A
  const int rB = qtB * 64 + w * 16;

  __shared__ __align__(16) _Float16 Klds[2][64 * 128];  // [buf][kv][d-swizzled]
  __shared__ __align__(16) _Float16 Vlds[2][128 * 64];  // [buf][d][kv-swizzled]
  __shared__ __align__(16) _Float16 Plds[4][16][72];    // per-wave P, padded

  // Q fragments in registers (softmax scale pre-folded)
  const _Float16* Qb = Qr + (size_t)bh * Tc * Dc;
  f16x8 qfA[4], qfB[4];
  #pragma unroll
  for (int kb = 0; kb < 4; ++kb) {
    qfA[kb] = *(const f16x8*)&Qb[(size_t)(rA + c16) * Dc + kb * 32 + g * 8];
    qfB[kb] = *(const f16x8*)&Qb[(size_t)(rB + c16) * Dc + kb * 32 + g * 8];
  }

  f32x4 accA[8] = {}, accB[8] = {};
  float mA[4], lA[4], mB[4], lB[4];
  #pragma unroll
  for (int r = 0; r < 4; ++r) { mA[r] = -1e30f; lA[r] = 0.f; mB[r] = -1e30f; lB[r] = 0.f; }

  const _Float16* Kt0 = Kr + (size_t)bh * Tc * Dc;

  auto stage = [&](int j, int buf) {
    const char* src = (const char*)(Kt0 + (size_t)j * 64 * Dc);
    #pragma unroll
    for (int i = 0; i < 4; ++i) {
      int ch = i * 4 + w;
      gload_lds16(src + ch * 1024 + lane * 16, (char*)(&Klds[buf][0]) + ch * 1024);
    }
    #pragma unroll
    for (int i = 0; i < 4; ++i) {
      int ch = i * 4 + w;
      int d = ch * 8 + (lane >> 3);
      const char* gs = (const char*)(Vt + ((size_t)bh * Dc + d) * Tc + j * 64) + (lane & 7) * 16;
      gload_lds16(gs, (char*)(&Vlds[buf][0]) + ch * 1024);
    }
  };

  // softmax + PV for one 16-row tile fragment
  auto process_tile = [&](f32x4* s, f32x4* acc, float* m, float* l,
                          int rT, int j, int cur, bool maskit) {
    if (maskit) {
      #pragma unroll
      for (int ni = 0; ni < 4; ++ni)
        #pragma unroll
        for (int r = 0; r < 4; ++r) {
          int q = rT + g * 4 + r;
          int kv = j * 64 + ni * 16 + c16;
          if (kv > q) s[ni][r] = -1e30f;
        }
    }
    #pragma unroll
    for (int r = 0; r < 4; ++r) {
      float mt = fmaxf(fmaxf(s[0][r], s[1][r]), fmaxf(s[2][r], s[3][r]));
      #pragma unroll
      for (int off = 1; off < 16; off <<= 1) mt = fmaxf(mt, __shfl_xor(mt, off));
      float mnew = fmaxf(m[r], mt);
      float alpha = __expf(m[r] - mnew);
      float p0 = __expf(s[0][r] - mnew), p1 = __expf(s[1][r] - mnew);
      float p2 = __expf(s[2][r] - mnew), p3 = __expf(s[3][r] - mnew);
      float ls = p0 + p1 + p2 + p3;
      #pragma unroll
      for (int off = 1; off < 16; off <<= 1) ls += __shfl_xor(ls, off);
      l[r] = l[r] * alpha + ls;
      m[r] = mnew;
      #pragma unroll
      for (int di = 0; di < 8; ++di) acc[di][r] *= alpha;
      int prow = g * 4 + r;
      Plds[w][prow][0  + c16] = (_Float16)p0;
      Plds[w][prow][16 + c16] = (_Float16)p1;
      Plds[w][prow][32 + c16] = (_Float16)p2;
      Plds[w][prow][48 + c16] = (_Float16)p3;
    }
    #pragma unroll
    for (int kvb = 0; kvb < 2; ++kvb) {
      f16x8 pf = *(const f16x8*)&Plds[w][c16][kvb * 32 + g * 8];
      __builtin_amdgcn_s_setprio(1);
      #pragma unroll
      for (int di = 0; di < 8; ++di) {
        f16x8 vf = *(const f16x8*)&Vlds[cur][(di * 16 + c16) * 64 + ((kvb * 4 + g) ^ l7) * 8];
        acc[di] = __builtin_amdgcn_mfma_f32_16x16x32_f16(pf, vf, acc[di], 0, 0, 0);
      }
      __builtin_amdgcn_s_setprio(0);
    }
  };

  const int nt = qtB + 1;
  stage(0, 0);
  __syncthreads();                            // compiler drains vmcnt here
  int cur = 0;
  for (int j = 0; j < nt; ++j) {
    if (j + 1 < nt) stage(j + 1, cur ^ 1);    // issue next tile's loads (overlap)
    const bool doA = (j <= qtA);

    // ---- QK^T for both tiles, K-fragments shared ----
    f32x4 sA[4] = {}, sB[4] = {};
    #pragma unroll
    for (int kb = 0; kb < 4; ++kb) {
      f16x8 bfr[4];
      #pragma unroll
      for (int ni = 0; ni < 4; ++ni)
        bfr[ni] = *(const f16x8*)&Klds[cur][(ni * 16 + c16) * 128 + ((kb * 4 + g) ^ l7) * 8];
      __builtin_amdgcn_s_setprio(1);
      #pragma unroll
      for (int ni = 0; ni < 4; ++ni) {
        sB[ni] = __builtin_amdgcn_mfma_f32_16x16x32_f16(qfB[kb], bfr[ni], sB[ni], 0, 0, 0);
        if (doA)
          sA[ni] = __builtin_amdgcn_mfma_f32_16x16x32_f16(qfA[kb], bfr[ni], sA[ni], 0, 0, 0);
      }
      __builtin_amdgcn_s_setprio(0);
    }

    process_tile(sB, accB, mB, lB, rB, j, cur, j == qtB);
    if (doA) process_tile(sA, accA, mA, lA, rA, j, cur, j == qtA);

    __syncthreads();                          // drains next-tile staging, protects buffers
    cur ^= 1;
  }

  // ---- epilogue: O /= l, write [B][T][C] fp16 ----
  const int b = bh >> 4, h = bh & 15;
  #pragma unroll
  for (int tile = 0; tile < 2; ++tile) {
    f32x4* acc = tile ? accB : accA;
    float* l   = tile ? lB   : lA;
    int rT     = tile ? rB   : rA;
    #pragma unroll
    for (int r = 0; r < 4; ++r) {
      float inv = 1.0f / l[r];
      int trow = rT + g * 4 + r;
      _Float16* orow = Oh + ((size_t)b * Tc + trow) * Cc + h * Dc;
      #pragma unroll
      for (int di = 0; di < 8; ++di)
        orow[di * 16 + c16] = (_Float16)(acc[di][r] * inv);
    }
  }
}

// ---------------- host launch ----------------
extern "C" void kernel_launch(void* const* d_in, const int* in_sizes, int n_in,
                              void* d_out, int out_size, void* d_ws, size_t ws_size,
                              hipStream_t stream) {
  const float* x      = (const float*)d_in[0];
  const float* cosT   = (const float*)d_in[1];
  const float* sinT   = (const float*)d_in[2];
  const float* W_attn = (const float*)d_in[3];
  const float* W_proj = (const float*)d_in[4];
  float* out = (float*)d_out;

  // workspace layout (bytes)
  const size_t OFF_XH   = 0;                       // 4096*2048*2   = 16,777,216
  const size_t OFF_WAH  = 16777216;                // 6144*2048*2   = 25,165,824
  const size_t OFF_WPH  = 41943040;                // 2048*2048*2   =  8,388,608
  const size_t OFF_QKV  = 50331648;                // 4096*6144*2   = 50,331,648
  const size_t OFF_QR   = 100663296;               // 16,777,216
  const size_t OFF_KR   = 117440512;               // 16,777,216
  const size_t OFF_VT   = 134217728;               // 16,777,216
  const size_t WS_NEEDED = 150994944;
  if (ws_size < WS_NEEDED) return;

  char* ws = (char*)d_ws;
  _Float16* xh   = (_Float16*)(ws + OFF_XH);
  _Float16* Wah  = (_Float16*)(ws + OFF_WAH);
  _Float16* Wph  = (_Float16*)(ws + OFF_WPH);
  _Float16* qkvh = (_Float16*)(ws + OFF_QKV);
  _Float16* Qr   = (_Float16*)(ws + OFF_QR);
  _Float16* Kr   = (_Float16*)(ws + OFF_KR);
  _Float16* Vt   = (_Float16*)(ws + OFF_VT);
  _Float16* Oh   = qkvh;   // reuse qkv buffer for attention output

  cvt_f16_kernel<<<dim3(8192), dim3(256), 0, stream>>>(x, xh, (Bc * Tc * Cc) / 4);
  transpose_cvt_kernel<<<dim3(N3 / 64, Cc / 64), dim3(256), 0, stream>>>(W_attn, Wah, Cc, N3);
  transpose_cvt_kernel<<<dim3(Cc / 64, Cc / 64), dim3(256), 0, stream>>>(W_proj, Wph, Cc, Cc);
  gemm_bt_kernel<true><<<dim3(N3 / 128, BT / 128), dim3(256), 0, stream>>>(xh, Wah, qkvh, BT, N3, Cc);
  rope_qk_kernel<<<dim3(BT), dim3(256), 0, stream>>>(qkvh, cosT, sinT, Qr, Kr);
  vtrans_kernel<<<dim3(Tc / 64, Dc / 64, Bc * Hc), dim3(256), 0, stream>>>(qkvh, Vt);
  attn_kernel<<<dim3(Bc * Hc, 16), dim3(256), 0, stream>>>(Qr, Kr, Vt, Oh);
  gemm_bt_kernel<false><<<dim3(Cc / 128, BT / 128), dim3(256), 0, stream>>>(Oh, Wph, out, BT, Cc, Cc);
}

// Round 6
// 405.898 us; speedup vs baseline: 1.3781x; 1.1032x over previous
//
#include <hip/hip_runtime.h>
#include <stdint.h>

// Shapes (fixed by the problem)
#define Bc   2
#define Tc   2048
#define Cc   2048
#define Hc   16
#define Dc   128
#define BT   4096      // B*T
#define N3   6144      // 3*C
#define QSCALE 0.08838834764831845f  // 1/sqrt(128)

typedef _Float16 f16x8 __attribute__((ext_vector_type(8)));
typedef _Float16 f16x4 __attribute__((ext_vector_type(4)));
typedef float    f32x4 __attribute__((ext_vector_type(4)));

__device__ __forceinline__ void gload_lds16(const void* g, void* l) {
  __builtin_amdgcn_global_load_lds(
      (__attribute__((address_space(1))) void*)(uintptr_t)g,
      (__attribute__((address_space(3))) void*)(unsigned int)(uintptr_t)l,
      16, 0, 0);
}

// ---------------- fp32 -> fp16 cast (vectorized) ----------------
__global__ __launch_bounds__(256) void cvt_f16_kernel(const float* __restrict__ in,
                                                      _Float16* __restrict__ out, int n4) {
  int i = blockIdx.x * 256 + threadIdx.x;
  if (i < n4) {
    float4 v = ((const float4*)in)[i];
    f16x4 o; o[0]=(_Float16)v.x; o[1]=(_Float16)v.y; o[2]=(_Float16)v.z; o[3]=(_Float16)v.w;
    ((f16x4*)out)[i] = o;
  }
}

// ---------------- W [K][N] fp32 -> Wt [N][K] fp16 (LDS-tiled transpose) ----------------
__global__ __launch_bounds__(256) void transpose_cvt_kernel(const float* __restrict__ W,
                                                            _Float16* __restrict__ Wt,
                                                            int K, int N) {
  const int n0 = blockIdx.x * 64, k0 = blockIdx.y * 64;
  __shared__ float tile[64][65];
  const int tid = threadIdx.x;
  #pragma unroll
  for (int i = 0; i < 4; ++i) {               // load 64x64 f32, coalesced rows
    int u = i * 256 + tid, r = u >> 4, s = u & 15;
    float4 v = *(const float4*)&W[(size_t)(k0 + r) * N + n0 + s * 4];
    tile[r][s*4+0] = v.x; tile[r][s*4+1] = v.y; tile[r][s*4+2] = v.z; tile[r][s*4+3] = v.w;
  }
  __syncthreads();
  #pragma unroll
  for (int i = 0; i < 2; ++i) {               // write 64 n-rows of 64 fp16, coalesced
    int u = i * 256 + tid, c = u >> 3, rg = u & 7;
    f16x8 o;
    #pragma unroll
    for (int j = 0; j < 8; ++j) o[j] = (_Float16)tile[rg * 8 + j][c];
    *(f16x8*)&Wt[(size_t)(n0 + c) * K + k0 + rg * 8] = o;
  }
}

// ================= 256x128 deep-pipelined GEMM =================
// C[M][N] = A[M][K] * Bt[N][K]^T, fp16 in, fp32 acc.
// BM=256 BN=128 BK=64, 512 threads = 8 waves (4M x 2N), per-wave 64x64 out.
// Double-buffered LDS (96 KB), raw s_barrier + counted vmcnt (never 0 in
// steady state), T2 XOR-swizzle (read side + inverse on global src), T5 setprio.
#define GLDS_BUF 49152   // bytes per buffer: A 256*64*2 = 32768, B 128*64*2 = 16384

template<bool OUT16>
__global__ __launch_bounds__(512, 2) void gemm256_kernel(const _Float16* __restrict__ A,
                                                         const _Float16* __restrict__ Bt,
                                                         void* __restrict__ C,
                                                         int M, int N, int K) {
  __shared__ __align__(16) char glds[2 * GLDS_BUF];
  const int tid = threadIdx.x;
  const int wid = tid >> 6, lane = tid & 63, g = lane >> 4, c16 = lane & 15;
  const int wr = wid >> 1, wc = wid & 1;

  // bijective XCD swizzle (grid % 8 == 0 by construction)
  const int nblocks = gridDim.x, chunk = nblocks >> 3;
  const int bid = blockIdx.x;
  const int sw = (bid & 7) * chunk + (bid >> 3);
  const int ntm = M >> 8;
  const int m0 = (sw % ntm) * 256, n0 = (sw / ntm) * 128;

  const int ntk = K >> 6;
  const int row8 = tid >> 3, s8 = tid & 7;
  const int scol = (s8 ^ (row8 & 7)) * 8;       // inverse-swizzled k-offset (f16 elems)
  const int swz = (c16 & 7) << 4;               // read-side XOR (bytes)

  // stage one K-tile (A 256x64 + B 128x64) into buffer bb, linear LDS dest,
  // swizzle pre-baked into the global source column.
  auto stage_tile = [&](char* bb, int kt) {
    #pragma unroll
    for (int c = 0; c < 4; ++c)
      gload_lds16(A + (size_t)(m0 + c * 64 + row8) * K + kt * 64 + scol,
                  bb + c * 8192 + tid * 16);
    #pragma unroll
    for (int c = 0; c < 2; ++c)
      gload_lds16(Bt + (size_t)(n0 + c * 64 + row8) * K + kt * 64 + scol,
                  bb + 32768 + c * 8192 + tid * 16);
  };

  f32x4 acc[4][4] = {};

  // prologue: stage tiles 0,1; drain tile 0 only (6 of 12 loads)
  stage_tile(glds, 0);
  stage_tile(glds + GLDS_BUF, 1);
  asm volatile("s_waitcnt vmcnt(6)" ::: "memory");
  __builtin_amdgcn_s_barrier();

  for (int t = 0; t < ntk; ++t) {
    char* bb = glds + (t & 1) * GLDS_BUF;

    // ---- phase A: k-step 0 ----
    f16x8 a0[4], b0[4];
    #pragma unroll
    for (int mi = 0; mi < 4; ++mi)
      a0[mi] = *(const f16x8*)(bb + (wr * 64 + mi * 16 + c16) * 128 + ((g * 16) ^ swz));
    #pragma unroll
    for (int ni = 0; ni < 4; ++ni)
      b0[ni] = *(const f16x8*)(bb + 32768 + (wc * 64 + ni * 16 + c16) * 128 + ((g * 16) ^ swz));
    __builtin_amdgcn_s_setprio(1);
    #pragma unroll
    for (int mi = 0; mi < 4; ++mi)
      #pragma unroll
      for (int ni = 0; ni < 4; ++ni)
        acc[mi][ni] = __builtin_amdgcn_mfma_f32_16x16x32_f16(a0[mi], b0[ni], acc[mi][ni], 0, 0, 0);
    __builtin_amdgcn_s_setprio(0);

    // ---- phase B: k-step 1 reads, then buffer handoff ----
    f16x8 a1[4], b1[4];
    #pragma unroll
    for (int mi = 0; mi < 4; ++mi)
      a1[mi] = *(const f16x8*)(bb + (wr * 64 + mi * 16 + c16) * 128 + ((64 + g * 16) ^ swz));
    #pragma unroll
    for (int ni = 0; ni < 4; ++ni)
      b1[ni] = *(const f16x8*)(bb + 32768 + (wc * 64 + ni * 16 + c16) * 128 + ((64 + g * 16) ^ swz));
    asm volatile("s_waitcnt lgkmcnt(0)" ::: "memory");  // my reads of bb retired
    __builtin_amdgcn_sched_barrier(0);
    __builtin_amdgcn_s_barrier();                        // all waves done reading bb
    if (t + 2 < ntk) {
      stage_tile(bb, t + 2);                             // overwrite bb with tile t+2
      asm volatile("s_waitcnt vmcnt(6)" ::: "memory");   // drain tile t+1, keep t+2 in flight
    } else if (t + 1 < ntk) {
      asm volatile("s_waitcnt vmcnt(0)" ::: "memory");   // tail: drain last tile
    }
    __builtin_amdgcn_s_barrier();                        // tile t+1 visible to all
    __builtin_amdgcn_s_setprio(1);
    #pragma unroll
    for (int mi = 0; mi < 4; ++mi)
      #pragma unroll
      for (int ni = 0; ni < 4; ++ni)
        acc[mi][ni] = __builtin_amdgcn_mfma_f32_16x16x32_f16(a1[mi], b1[ni], acc[mi][ni], 0, 0, 0);
    __builtin_amdgcn_s_setprio(0);
  }

  #pragma unroll
  for (int mi = 0; mi < 4; ++mi)
    #pragma unroll
    for (int ni = 0; ni < 4; ++ni) {
      int row = m0 + wr * 64 + mi * 16 + g * 4;
      int col = n0 + wc * 64 + ni * 16 + c16;
      #pragma unroll
      for (int r = 0; r < 4; ++r) {
        if constexpr (OUT16) ((_Float16*)C)[(size_t)(row + r) * N + col] = (_Float16)acc[mi][ni][r];
        else                 ((float*)C)[(size_t)(row + r) * N + col]    = acc[mi][ni][r];
      }
    }
}

// ---------------- RoPE on q,k; fold softmax scale into Q; K stored bank-swizzled ----------------
__global__ __launch_bounds__(256) void rope_qk_kernel(const _Float16* __restrict__ qkv,
                                                      const float* __restrict__ cosT,
                                                      const float* __restrict__ sinT,
                                                      _Float16* __restrict__ Qr,
                                                      _Float16* __restrict__ Kr) {
  const int bt = blockIdx.x;                 // b*T + t
  const int b = bt >> 11, t = bt & 2047;
  const int tid = threadIdx.x;
  const _Float16* row = qkv + (size_t)bt * N3;
  const int sw = (t & 7) * 8;
  #pragma unroll
  for (int i = 0; i < 4; ++i) {
    int p = i * 256 + tid;                   // pair index: h = p/64, d = p%64 (d < 64)
    int h = p >> 6, d = p & 63;
    float cs = cosT[t * Dc + d], sn = sinT[t * Dc + d];
    float ql = (float)row[h * Dc + d],        qh = (float)row[h * Dc + d + 64];
    float kl = (float)row[Cc + h * Dc + d],   kh = (float)row[Cc + h * Dc + d + 64];
    float q0 = ql * cs - qh * sn, q1 = qh * cs + ql * sn;
    float k0 = kl * cs - kh * sn, k1 = kh * cs + kl * sn;
    size_t obase = ((size_t)(b * Hc + h) * Tc + t) * Dc;
    Qr[obase + d]        = (_Float16)(q0 * QSCALE);
    Qr[obase + d + 64]   = (_Float16)(q1 * QSCALE);
    Kr[obase + (d ^ sw)]        = (_Float16)k0;    // pre-baked XOR swizzle
    Kr[obase + ((d + 64) ^ sw)] = (_Float16)k1;
  }
}

// ---------------- V transpose: qkv v-part -> Vt[B][H][D][T] fp16, pre-swizzled ----------------
__global__ __launch_bounds__(256) void vtrans_kernel(const _Float16* __restrict__ qkv,
                                                     _Float16* __restrict__ Vt) {
  const int t0 = blockIdx.x * 64, d0 = blockIdx.y * 64, bh = blockIdx.z;
  const int b = bh >> 4, h = bh & 15;
  __shared__ __align__(16) _Float16 tile[64][72];
  const int tid = threadIdx.x;
  #pragma unroll
  for (int i = 0; i < 2; ++i) {
    int u = i * 256 + tid, tr = u >> 3, sg = u & 7;
    f16x8 v = *(const f16x8*)&qkv[((size_t)b * Tc + t0 + tr) * N3 + 2 * Cc + h * Dc + d0 + sg * 8];
    *(f16x8*)&tile[tr][sg * 8] = v;
  }
  __syncthreads();
  #pragma unroll
  for (int i = 0; i < 2; ++i) {
    int u = i * 256 + tid, dl = u >> 3, tg = u & 7;
    int d = d0 + dl;
    f16x8 o;
    #pragma unroll
    for (int j = 0; j < 8; ++j) o[j] = tile[tg * 8 + j][dl];
    size_t off = ((size_t)bh * Dc + d) * Tc + t0 + ((tg ^ (d & 7)) * 8);  // swizzled t
    *(f16x8*)&Vt[off] = o;
  }
}

// ---------------- Flash attention (causal), balanced pairs + double-buffered staging ----
__global__ __launch_bounds__(256, 2) void attn_kernel(const _Float16* __restrict__ Qr,
                                                      const _Float16* __restrict__ Kr,
                                                      const _Float16* __restrict__ Vt,
                                                      _Float16* __restrict__ Oh) {
  const int bh = blockIdx.x;                 // fast dim -> XCD = bh % 8 (L2 locality)
  const int pr = blockIdx.y;                 // pair index 0..15
  const int qtA = pr, qtB = 31 - pr;
  const int tid = threadIdx.x;
  const int w = tid >> 6, lane = tid & 63, g = lane >> 4, c16 = lane & 15, l7 = lane & 7;
  const int rA = qtA * 64 + w * 16;          // wave's 16 rows in tile A
  const int rB = qtB * 64 + w * 16;

  __shared__ __align__(16) _Float16 Klds[2][64 * 128];  // [buf][kv][d-swizzled]
  __shared__ __align__(16) _Float16 Vlds[2][128 * 64];  // [buf][d][kv-swizzled]
  __shared__ __align__(16) _Float16 Plds[4][16][72];    // per-wave P, padded

  // Q fragments in registers (softmax scale pre-folded)
  const _Float16* Qb = Qr + (size_t)bh * Tc * Dc;
  f16x8 qfA[4], qfB[4];
  #pragma unroll
  for (int kb = 0; kb < 4; ++kb) {
    qfA[kb] = *(const f16x8*)&Qb[(size_t)(rA + c16) * Dc + kb * 32 + g * 8];
    qfB[kb] = *(const f16x8*)&Qb[(size_t)(rB + c16) * Dc + kb * 32 + g * 8];
  }

  f32x4 accA[8] = {}, accB[8] = {};
  float mA[4], lA[4], mB[4], lB[4];
  #pragma unroll
  for (int r = 0; r < 4; ++r) { mA[r] = -1e30f; lA[r] = 0.f; mB[r] = -1e30f; lB[r] = 0.f; }

  const _Float16* Kt0 = Kr + (size_t)bh * Tc * Dc;

  auto stage = [&](int j, int buf) {
    const char* src = (const char*)(Kt0 + (size_t)j * 64 * Dc);
    #pragma unroll
    for (int i = 0; i < 4; ++i) {
      int ch = i * 4 + w;
      gload_lds16(src + ch * 1024 + lane * 16, (char*)(&Klds[buf][0]) + ch * 1024);
    }
    #pragma unroll
    for (int i = 0; i < 4; ++i) {
      int ch = i * 4 + w;
      int d = ch * 8 + (lane >> 3);
      const char* gs = (const char*)(Vt + ((size_t)bh * Dc + d) * Tc + j * 64) + (lane & 7) * 16;
      gload_lds16(gs, (char*)(&Vlds[buf][0]) + ch * 1024);
    }
  };

  // softmax + PV for one 16-row tile fragment
  auto process_tile = [&](f32x4* s, f32x4* acc, float* m, float* l,
                          int rT, int j, int cur, bool maskit) {
    if (maskit) {
      #pragma unroll
      for (int ni = 0; ni < 4; ++ni)
        #pragma unroll
        for (int r = 0; r < 4; ++r) {
          int q = rT + g * 4 + r;
          int kv = j * 64 + ni * 16 + c16;
          if (kv > q) s[ni][r] = -1e30f;
        }
    }
    #pragma unroll
    for (int r = 0; r < 4; ++r) {
      float mt = fmaxf(fmaxf(s[0][r], s[1][r]), fmaxf(s[2][r], s[3][r]));
      #pragma unroll
      for (int off = 1; off < 16; off <<= 1) mt = fmaxf(mt, __shfl_xor(mt, off));
      float mnew = fmaxf(m[r], mt);
      float alpha = __expf(m[r] - mnew);
      float p0 = __expf(s[0][r] - mnew), p1 = __expf(s[1][r] - mnew);
      float p2 = __expf(s[2][r] - mnew), p3 = __expf(s[3][r] - mnew);
      float ls = p0 + p1 + p2 + p3;
      #pragma unroll
      for (int off = 1; off < 16; off <<= 1) ls += __shfl_xor(ls, off);
      l[r] = l[r] * alpha + ls;
      m[r] = mnew;
      #pragma unroll
      for (int di = 0; di < 8; ++di) acc[di][r] *= alpha;
      int prow = g * 4 + r;
      Plds[w][prow][0  + c16] = (_Float16)p0;
      Plds[w][prow][16 + c16] = (_Float16)p1;
      Plds[w][prow][32 + c16] = (_Float16)p2;
      Plds[w][prow][48 + c16] = (_Float16)p3;
    }
    #pragma unroll
    for (int kvb = 0; kvb < 2; ++kvb) {
      f16x8 pf = *(const f16x8*)&Plds[w][c16][kvb * 32 + g * 8];
      __builtin_amdgcn_s_setprio(1);
      #pragma unroll
      for (int di = 0; di < 8; ++di) {
        f16x8 vf = *(const f16x8*)&Vlds[cur][(di * 16 + c16) * 64 + ((kvb * 4 + g) ^ l7) * 8];
        acc[di] = __builtin_amdgcn_mfma_f32_16x16x32_f16(pf, vf, acc[di], 0, 0, 0);
      }
      __builtin_amdgcn_s_setprio(0);
    }
  };

  const int nt = qtB + 1;
  stage(0, 0);
  __syncthreads();                            // compiler drains vmcnt here
  int cur = 0;
  for (int j = 0; j < nt; ++j) {
    if (j + 1 < nt) stage(j + 1, cur ^ 1);    // issue next tile's loads (overlap)
    const bool doA = (j <= qtA);

    // ---- QK^T for both tiles, K-fragments shared ----
    f32x4 sA[4] = {}, sB[4] = {};
    #pragma unroll
    for (int kb = 0; kb < 4; ++kb) {
      f16x8 bfr[4];
      #pragma unroll
      for (int ni = 0; ni < 4; ++ni)
        bfr[ni] = *(const f16x8*)&Klds[cur][(ni * 16 + c16) * 128 + ((kb * 4 + g) ^ l7) * 8];
      __builtin_amdgcn_s_setprio(1);
      #pragma unroll
      for (int ni = 0; ni < 4; ++ni) {
        sB[ni] = __builtin_amdgcn_mfma_f32_16x16x32_f16(qfB[kb], bfr[ni], sB[ni], 0, 0, 0);
        if (doA)
          sA[ni] = __builtin_amdgcn_mfma_f32_16x16x32_f16(qfA[kb], bfr[ni], sA[ni], 0, 0, 0);
      }
      __builtin_amdgcn_s_setprio(0);
    }

    process_tile(sB, accB, mB, lB, rB, j, cur, j == qtB);
    if (doA) process_tile(sA, accA, mA, lA, rA, j, cur, j == qtA);

    __syncthreads();                          // drains next-tile staging, protects buffers
    cur ^= 1;
  }

  // ---- epilogue: O /= l, write [B][T][C] fp16 ----
  const int b = bh >> 4, h = bh & 15;
  #pragma unroll
  for (int tile = 0; tile < 2; ++tile) {
    f32x4* acc = tile ? accB : accA;
    float* l   = tile ? lB   : lA;
    int rT     = tile ? rB   : rA;
    #pragma unroll
    for (int r = 0; r < 4; ++r) {
      float inv = 1.0f / l[r];
      int trow = rT + g * 4 + r;
      _Float16* orow = Oh + ((size_t)b * Tc + trow) * Cc + h * Dc;
      #pragma unroll
      for (int di = 0; di < 8; ++di)
        orow[di * 16 + c16] = (_Float16)(acc[di][r] * inv);
    }
  }
}

// ---------------- host launch ----------------
extern "C" void kernel_launch(void* const* d_in, const int* in_sizes, int n_in,
                              void* d_out, int out_size, void* d_ws, size_t ws_size,
                              hipStream_t stream) {
  const float* x      = (const float*)d_in[0];
  const float* cosT   = (const float*)d_in[1];
  const float* sinT   = (const float*)d_in[2];
  const float* W_attn = (const float*)d_in[3];
  const float* W_proj = (const float*)d_in[4];
  float* out = (float*)d_out;

  // workspace layout (bytes)
  const size_t OFF_XH   = 0;                       // 4096*2048*2   = 16,777,216
  const size_t OFF_WAH  = 16777216;                // 6144*2048*2   = 25,165,824
  const size_t OFF_WPH  = 41943040;                // 2048*2048*2   =  8,388,608
  const size_t OFF_QKV  = 50331648;                // 4096*6144*2   = 50,331,648
  const size_t OFF_QR   = 100663296;               // 16,777,216
  const size_t OFF_KR   = 117440512;               // 16,777,216
  const size_t OFF_VT   = 134217728;               // 16,777,216
  const size_t WS_NEEDED = 150994944;
  if (ws_size < WS_NEEDED) return;

  char* ws = (char*)d_ws;
  _Float16* xh   = (_Float16*)(ws + OFF_XH);
  _Float16* Wah  = (_Float16*)(ws + OFF_WAH);
  _Float16* Wph  = (_Float16*)(ws + OFF_WPH);
  _Float16* qkvh = (_Float16*)(ws + OFF_QKV);
  _Float16* Qr   = (_Float16*)(ws + OFF_QR);
  _Float16* Kr   = (_Float16*)(ws + OFF_KR);
  _Float16* Vt   = (_Float16*)(ws + OFF_VT);
  _Float16* Oh   = qkvh;   // reuse qkv buffer for attention output

  cvt_f16_kernel<<<dim3(8192), dim3(256), 0, stream>>>(x, xh, (Bc * Tc * Cc) / 4);
  transpose_cvt_kernel<<<dim3(N3 / 64, Cc / 64), dim3(256), 0, stream>>>(W_attn, Wah, Cc, N3);
  transpose_cvt_kernel<<<dim3(Cc / 64, Cc / 64), dim3(256), 0, stream>>>(W_proj, Wph, Cc, Cc);
  // qkv GEMM: M=4096 N=6144 K=2048 -> grid 16*48 = 768 blocks (3.0/CU)
  gemm256_kernel<true><<<dim3((BT / 256) * (N3 / 128)), dim3(512), 0, stream>>>(xh, Wah, qkvh, BT, N3, Cc);
  rope_qk_kernel<<<dim3(BT), dim3(256), 0, stream>>>(qkvh, cosT, sinT, Qr, Kr);
  vtrans_kernel<<<dim3(Tc / 64, Dc / 64, Bc * Hc), dim3(256), 0, stream>>>(qkvh, Vt);
  attn_kernel<<<dim3(Bc * Hc, 16), dim3(256), 0, stream>>>(Qr, Kr, Vt, Oh);
  // out GEMM: M=4096 N=2048 K=2048 -> grid 16*16 = 256 blocks (1.0/CU)
  gemm256_kernel<false><<<dim3((BT / 256) * (Cc / 128)), dim3(512), 0, stream>>>(Oh, Wph, out, BT, Cc, Cc);
}